// Round 5
// baseline (45529.175 us; speedup 1.0000x reference)
//
#include <hip/hip_runtime.h>
#include <hip/hip_fp16.h>

#define BB 8
#define SS 4096
#define II 512
#define HH 512

typedef _Float16 f16x8 __attribute__((ext_vector_type(8)));
typedef float f32x4 __attribute__((ext_vector_type(4)));

__device__ __forceinline__ float tanh_fast(float x) {
    // tanh(x) = 1 - 2/(exp2(2*log2e*x)+1); saturates correctly at +-inf
    float e = __builtin_amdgcn_exp2f(2.885390081777927f * x);
    return 1.0f - 2.0f * __builtin_amdgcn_rcpf(e + 1.0f);
}

// ---------------------------------------------------------------------------
// Phase 1: xp[m][n] = x[m][:] @ W_ih[n][:] + b_ih[n] + b_hh[n]   (b_hh folded)
// ---------------------------------------------------------------------------
#define P1_TM 64
#define P1_TN 64
#define P1_TK 16
#define P1_LDP 68

__global__ __launch_bounds__(256) void xp_gemm(const float* __restrict__ x,
                                               const float* __restrict__ wih,
                                               const float* __restrict__ bih,
                                               const float* __restrict__ bhh,
                                               float* __restrict__ out) {
    __shared__ float As[P1_TK][P1_LDP];
    __shared__ float Bs[P1_TK][P1_LDP];
    const int tid = threadIdx.x;
    const int n0  = blockIdx.x * P1_TN;
    const int m0  = blockIdx.y * P1_TM;
    const int row = tid >> 2;
    const int f4  = tid & 3;
    const int ty  = tid >> 4;
    const int tx  = tid & 15;

    float acc[4][4];
#pragma unroll
    for (int r = 0; r < 4; ++r)
#pragma unroll
        for (int c = 0; c < 4; ++c) acc[r][c] = 0.0f;

    const float* xa = x   + (size_t)(m0 + row) * II + f4 * 4;
    const float* wb = wih + (size_t)(n0 + row) * II + f4 * 4;

    for (int kb = 0; kb < II; kb += P1_TK) {
        float4 av = *(const float4*)(xa + kb);
        float4 bv = *(const float4*)(wb + kb);
        __syncthreads();
        As[f4 * 4 + 0][row] = av.x; As[f4 * 4 + 1][row] = av.y;
        As[f4 * 4 + 2][row] = av.z; As[f4 * 4 + 3][row] = av.w;
        Bs[f4 * 4 + 0][row] = bv.x; Bs[f4 * 4 + 1][row] = bv.y;
        Bs[f4 * 4 + 2][row] = bv.z; Bs[f4 * 4 + 3][row] = bv.w;
        __syncthreads();
#pragma unroll
        for (int kk = 0; kk < P1_TK; ++kk) {
            const float* a4 = &As[kk][ty * 4];
            const float* b4 = &Bs[kk][tx * 4];
#pragma unroll
            for (int r = 0; r < 4; ++r)
#pragma unroll
                for (int c = 0; c < 4; ++c)
                    acc[r][c] = fmaf(a4[r], b4[c], acc[r][c]);
        }
    }

    const float4 b1 = *(const float4*)&bih[n0 + tx * 4];
    const float4 b2 = *(const float4*)&bhh[n0 + tx * 4];
#pragma unroll
    for (int r = 0; r < 4; ++r) {
        float4 v;
        v.x = acc[r][0] + b1.x + b2.x;
        v.y = acc[r][1] + b1.y + b2.y;
        v.z = acc[r][2] + b1.z + b2.z;
        v.w = acc[r][3] + b1.w + b2.w;
        *(float4*)(out + (size_t)(m0 + ty * 4 + r) * HH + n0 + tx * 4) = v;
    }
}

// ---------------------------------------------------------------------------
// Phase 2: 1 CU, 8 waves (512 threads). Wave w owns n in [64w, 64w+64) =
// 4 tiles; tiles 0..2 -> W B-frags in regs, tile 3 -> LDS stream. All 8
// batches in M of mfma_f32_16x16x32_f16; A rows 8..15 alias rows 0..7.
// A-frags in 8KB double buffer, 1 barrier/step.
// r5: odd waves run kb rotated by 8 (de-correlates SIMD wave pairs so one
// wave's MFMA phase covers the sibling's ds_read phase), 4-kb chunks (deeper
// ds pipelining, still caps VGPR hoisting), setprio(1) around MFMA cluster.
// ---------------------------------------------------------------------------
#define WLDS_B   (8 * 16 * 1024)       // 131072: 8 waves x 16KB streamed W tile
#define ABUF_OFF WLDS_B
#define LDS_TOT4 (WLDS_B + 2 * 8192)   // 147456 <= 163840

__device__ __forceinline__ f16x8 ldw(const float* __restrict__ whh, int n,
                                     int kb, int lq) {
    const float* p = whh + (size_t)n * HH + kb * 32 + lq * 8;
    float4 a = *(const float4*)p;
    float4 b = *(const float4*)(p + 4);
    f16x8 f;
    f[0] = (_Float16)a.x; f[1] = (_Float16)a.y;
    f[2] = (_Float16)a.z; f[3] = (_Float16)a.w;
    f[4] = (_Float16)b.x; f[5] = (_Float16)b.y;
    f[6] = (_Float16)b.z; f[7] = (_Float16)b.w;
    return f;
}

__global__ __launch_bounds__(512, 2) void rnn_scan5(const float* __restrict__ whh,
                                                    float* __restrict__ io) {
    extern __shared__ char lds[];
    const int tid = threadIdx.x;
    const int w   = tid >> 6;        // wave 0..7
    const int l   = tid & 63;
    const int l15 = l & 15;
    const int lq  = l >> 4;          // 0..3
    const int m8  = l15 & 7;
    const int mb  = (lq & 1) * 4;    // batch-row base this lane outputs
    const int rot = (w & 1) * 8;     // kb rotation for odd waves

    // ---- W fragments: reg tiles gi=0..2, LDS tile gi=3 (lane-private)
    f16x8 wf0[16], wf1[16], wf2[16];
#pragma unroll
    for (int kb = 0; kb < 16; ++kb) {
        wf0[kb] = ldw(whh, w * 64 + 0 * 16 + l15, kb, lq);
        wf1[kb] = ldw(whh, w * 64 + 1 * 16 + l15, kb, lq);
        wf2[kb] = ldw(whh, w * 64 + 2 * 16 + l15, kb, lq);
        *(f16x8*)(lds + w * 16384 + kb * 1024 + l * 16) =
            ldw(whh, w * 64 + 3 * 16 + l15, kb, lq);
    }
    const char* wp = lds + w * 16384 + l * 16;

    // ---- per-lane output columns (s=0,1): gi = (lq>>1)*2 + s
    int xoff[2][4];   // global byte offsets: (mb+r)*SS*HH*4 + n_s*4
    int dsoff[2];     // A-buf scatter base (within one 8KB buffer)
#pragma unroll
    for (int s = 0; s < 2; ++s) {
        const int gi = (lq >> 1) * 2 + s;
        const int n  = w * 64 + gi * 16 + l15;
#pragma unroll
        for (int r = 0; r < 4; ++r)
            xoff[s][r] = (mb + r) * (SS * HH * 4) + n * 4;
        const int kb = n >> 5, ku = (n >> 3) & 3, ko = n & 7;
        dsoff[s] = kb * 512 + ku * 128 + ((mb ^ ((kb & 1) << 2)) * 16) + ko * 2;
    }

    __syncthreads();

#pragma unroll 1
    for (int t = 0; t < SS; ++t) {
        const char* pb = (const char*)io + (size_t)t * (HH * 4);

        // issue xp loads early (consumed in epilogue, hidden under MFMA)
        float xv[2][4];
#pragma unroll
        for (int s = 0; s < 2; ++s)
#pragma unroll
            for (int r = 0; r < 4; ++r)
                xv[s][r] = *(const float*)(pb + xoff[s][r]);

        f32x4 acc0 = {0.f, 0.f, 0.f, 0.f}, acc1 = acc0, acc2 = acc0, acc3 = acc0;

        if (t > 0) {
            const unsigned rb = ABUF_OFF + (unsigned)(((t & 1) ^ 1) * 8192);
            const char* aE = lds + rb + lq * 128 + m8 * 16;
            const char* aO = lds + rb + lq * 128 + ((m8 ^ 4) * 16);
            __builtin_amdgcn_s_setprio(1);
#pragma unroll
            for (int c = 0; c < 4; ++c) {   // 4-kb chunks
                __builtin_amdgcn_sched_barrier(0);
#pragma unroll
                for (int k4 = 0; k4 < 4; ++k4) {
                    const int kb = (c * 4 + k4 + rot) & 15;
                    f16x8 af = *(const f16x8*)(((kb & 1) ? aO : aE) + kb * 512);
                    f16x8 wl = *(const f16x8*)(wp + kb * 1024);
                    acc0 = __builtin_amdgcn_mfma_f32_16x16x32_f16(af, wf0[kb], acc0, 0, 0, 0);
                    acc1 = __builtin_amdgcn_mfma_f32_16x16x32_f16(af, wf1[kb], acc1, 0, 0, 0);
                    acc2 = __builtin_amdgcn_mfma_f32_16x16x32_f16(af, wf2[kb], acc2, 0, 0, 0);
                    acc3 = __builtin_amdgcn_mfma_f32_16x16x32_f16(af, wl,      acc3, 0, 0, 0);
                }
            }
            __builtin_amdgcn_sched_barrier(0);
            __builtin_amdgcn_s_setprio(0);
        }

        // epilogue: tanh, global store (overwrite xp[t] with h[t]), A-scatter
        char* wB = lds + ABUF_OFF + (t & 1) * 8192;
#pragma unroll
        for (int s = 0; s < 2; ++s) {
#pragma unroll
            for (int r = 0; r < 4; ++r) {
                const float aa = (lq < 2)
                    ? (s == 0 ? acc0[r] : acc1[r])
                    : (s == 0 ? acc2[r] : acc3[r]);
                const float v = tanh_fast(aa + xv[s][r]);
                *(float*)(pb + xoff[s][r]) = v;
                *(_Float16*)(wB + dsoff[s] + r * 16) = (_Float16)v;
            }
        }
        __syncthreads();
    }
}

// ---------------------------------------------------------------------------
extern "C" void kernel_launch(void* const* d_in, const int* in_sizes, int n_in,
                              void* d_out, int out_size, void* d_ws, size_t ws_size,
                              hipStream_t stream) {
    const float* x   = (const float*)d_in[0];
    const float* wih = (const float*)d_in[1];
    const float* whh = (const float*)d_in[2];
    const float* bih = (const float*)d_in[3];
    const float* bhh = (const float*)d_in[4];
    float* out = (float*)d_out;

    dim3 g1(HH / P1_TN, (BB * SS) / P1_TM);
    xp_gemm<<<g1, 256, 0, stream>>>(x, wih, bih, bhh, out);

    static_assert(LDS_TOT4 <= 163840, "LDS over 160 KiB");
    hipFuncSetAttribute((const void*)rnn_scan5,
                        hipFuncAttributeMaxDynamicSharedMemorySize, LDS_TOT4);
    rnn_scan5<<<dim3(1), dim3(512), LDS_TOT4, stream>>>(whh, out);
}

// Round 6
// 11327.168 us; speedup vs baseline: 4.0195x; 4.0195x over previous
//
#include <hip/hip_runtime.h>
#include <hip/hip_fp16.h>

#define BB 8
#define SS 4096
#define II 512
#define HH 512

typedef _Float16 f16x8 __attribute__((ext_vector_type(8)));
typedef float f32x4 __attribute__((ext_vector_type(4)));
typedef int i32x4 __attribute__((ext_vector_type(4)));

__device__ __forceinline__ float tanh_fast(float x) {
    // tanh(x) = 1 - 2/(exp2(2*log2e*x)+1); saturates correctly at +-inf
    float e = __builtin_amdgcn_exp2f(2.885390081777927f * x);
    return 1.0f - 2.0f * __builtin_amdgcn_rcpf(e + 1.0f);
}

// ---------------------------------------------------------------------------
// Phase 1: xp[m][n] = x[m][:] @ W_ih[n][:] + b_ih[n] + b_hh[n]   (b_hh folded)
// ---------------------------------------------------------------------------
#define P1_TM 64
#define P1_TN 64
#define P1_TK 16
#define P1_LDP 68

__global__ __launch_bounds__(256) void xp_gemm(const float* __restrict__ x,
                                               const float* __restrict__ wih,
                                               const float* __restrict__ bih,
                                               const float* __restrict__ bhh,
                                               float* __restrict__ out) {
    __shared__ float As[P1_TK][P1_LDP];
    __shared__ float Bs[P1_TK][P1_LDP];
    const int tid = threadIdx.x;
    const int n0  = blockIdx.x * P1_TN;
    const int m0  = blockIdx.y * P1_TM;
    const int row = tid >> 2;
    const int f4  = tid & 3;
    const int ty  = tid >> 4;
    const int tx  = tid & 15;

    float acc[4][4];
#pragma unroll
    for (int r = 0; r < 4; ++r)
#pragma unroll
        for (int c = 0; c < 4; ++c) acc[r][c] = 0.0f;

    const float* xa = x   + (size_t)(m0 + row) * II + f4 * 4;
    const float* wb = wih + (size_t)(n0 + row) * II + f4 * 4;

    for (int kb = 0; kb < II; kb += P1_TK) {
        float4 av = *(const float4*)(xa + kb);
        float4 bv = *(const float4*)(wb + kb);
        __syncthreads();
        As[f4 * 4 + 0][row] = av.x; As[f4 * 4 + 1][row] = av.y;
        As[f4 * 4 + 2][row] = av.z; As[f4 * 4 + 3][row] = av.w;
        Bs[f4 * 4 + 0][row] = bv.x; Bs[f4 * 4 + 1][row] = bv.y;
        Bs[f4 * 4 + 2][row] = bv.z; Bs[f4 * 4 + 3][row] = bv.w;
        __syncthreads();
#pragma unroll
        for (int kk = 0; kk < P1_TK; ++kk) {
            const float* a4 = &As[kk][ty * 4];
            const float* b4 = &Bs[kk][tx * 4];
#pragma unroll
            for (int r = 0; r < 4; ++r)
#pragma unroll
                for (int c = 0; c < 4; ++c)
                    acc[r][c] = fmaf(a4[r], b4[c], acc[r][c]);
        }
    }

    const float4 b1 = *(const float4*)&bih[n0 + tx * 4];
    const float4 b2 = *(const float4*)&bhh[n0 + tx * 4];
#pragma unroll
    for (int r = 0; r < 4; ++r) {
        float4 v;
        v.x = acc[r][0] + b1.x + b2.x;
        v.y = acc[r][1] + b1.y + b2.y;
        v.z = acc[r][2] + b1.z + b2.z;
        v.w = acc[r][3] + b1.w + b2.w;
        *(float4*)(out + (size_t)(m0 + ty * 4 + r) * HH + n0 + tx * 4) = v;
    }
}

// ---------------------------------------------------------------------------
// Phase 2: 1 CU, 8 waves. Wave w owns n in [64w,64w+64) = tiles g0..g3.
// g0,g1 full + g2 kb0..14 pinned in AGPRs (188 a-regs) via asm class-cast;
// g2 kb15 + g3 stream from LDS (17 KB/wave). All 8 batches in M of
// mfma_f32_16x16x32_f16; A rows 8..15 alias rows 0..7 (broadcast), so all
// lanes hold valid outputs. A-buf: plain h[m][n] fp16, row pitch 1056 B
// (2-way bank aliasing only), double-buffered, 1 barrier/step.
// ---------------------------------------------------------------------------
#define WLDS_B   (8 * 17408)            // 139264: per-wave 17KB streamed W
#define ABUF_P   1056                   // h row pitch (bytes)
#define ABUF_SZ  (8 * ABUF_P)           // 8448 per buffer
#define LDS_TOT6 (WLDS_B + 2 * ABUF_SZ) // 156160 <= 163840

__device__ __forceinline__ f16x8 ldw(const float* __restrict__ whh, int n,
                                     int kb, int lq) {
    const float* p = whh + (size_t)n * HH + kb * 32 + lq * 8;
    float4 a = *(const float4*)p;
    float4 b = *(const float4*)(p + 4);
    f16x8 f;
    f[0] = (_Float16)a.x; f[1] = (_Float16)a.y;
    f[2] = (_Float16)a.z; f[3] = (_Float16)a.w;
    f[4] = (_Float16)b.x; f[5] = (_Float16)b.y;
    f[6] = (_Float16)b.z; f[7] = (_Float16)b.w;
    return f;
}

#define MFMA16(a, b, c) __builtin_amdgcn_mfma_f32_16x16x32_f16((a), (b), (c), 0, 0, 0)
#define BC16(x) __builtin_bit_cast(f16x8, (x))

__global__ __launch_bounds__(512, 2) void rnn_scan6(const float* __restrict__ whh,
                                                    float* __restrict__ io) {
    extern __shared__ char lds[];
    const int tid = threadIdx.x;
    const int w   = tid >> 6;        // wave 0..7
    const int l   = tid & 63;
    const int l15 = l & 15;
    const int lq  = l >> 4;          // 0..3
    const int mb  = (lq & 1) * 4;    // batch-row base this lane outputs

    // ---- W fragments: g0,g1 (16 kb) + g2 kb0..14 in AGPRs
    i32x4 g0[16], g1[16], g2[15];
#pragma unroll
    for (int kb = 0; kb < 16; ++kb) {
        g0[kb] = __builtin_bit_cast(i32x4, ldw(whh, w * 64 + 0 * 16 + l15, kb, lq));
        asm("" : "+a"(g0[kb]));
        g1[kb] = __builtin_bit_cast(i32x4, ldw(whh, w * 64 + 1 * 16 + l15, kb, lq));
        asm("" : "+a"(g1[kb]));
    }
#pragma unroll
    for (int kb = 0; kb < 15; ++kb) {
        g2[kb] = __builtin_bit_cast(i32x4, ldw(whh, w * 64 + 2 * 16 + l15, kb, lq));
        asm("" : "+a"(g2[kb]));
    }
    // ---- LDS W: g3 all kb (offsets kb*1024), g2 kb15 (offset 16384)
    {
        char* wl = lds + w * 17408 + l * 16;
#pragma unroll
        for (int kb = 0; kb < 16; ++kb)
            *(f16x8*)(wl + kb * 1024) = ldw(whh, w * 64 + 3 * 16 + l15, kb, lq);
        *(f16x8*)(wl + 16384) = ldw(whh, w * 64 + 2 * 16 + l15, 15, lq);
    }
    const char* wr = lds + w * 17408 + l * 16;

    // ---- per-lane output columns (s=0,1): gi = (lq>>1)*2 + s
    int xoff[2][4];   // global byte offsets: (mb+r)*SS*HH*4 + n_s*4
    int nn[2];
#pragma unroll
    for (int s = 0; s < 2; ++s) {
        const int gi = (lq >> 1) * 2 + s;
        nn[s] = w * 64 + gi * 16 + l15;
#pragma unroll
        for (int r = 0; r < 4; ++r)
            xoff[s][r] = (mb + r) * (SS * HH * 4) + nn[s] * 4;
    }
    // A-read base offset within a buffer (lane-static part)
    const int ard = (l15 & 7) * ABUF_P + lq * 16;
    // A-write base offsets (per s), + r*ABUF_P immediates
    const int awr0 = mb * ABUF_P + nn[0] * 2;
    const int awr1 = mb * ABUF_P + nn[1] * 2;

    __syncthreads();

#pragma unroll 1
    for (int t = 0; t < SS; ++t) {
        const char* pb = (const char*)io + (size_t)t * (HH * 4);

        // issue xp loads early (consumed in epilogue, hidden under MFMA)
        float xv[2][4];
#pragma unroll
        for (int s = 0; s < 2; ++s)
#pragma unroll
            for (int r = 0; r < 4; ++r)
                xv[s][r] = *(const float*)(pb + xoff[s][r]);

        f32x4 acc0 = {0.f, 0.f, 0.f, 0.f}, acc1 = acc0, acc2 = acc0, acc3 = acc0;

        if (t > 0) {
            const char* ar = lds + WLDS_B + (((t & 1) ^ 1) * ABUF_SZ) + ard;
#pragma unroll
            for (int c = 0; c < 8; ++c) {   // 2-kb chunks, reg-pressure capped
                __builtin_amdgcn_sched_barrier(0);
#pragma unroll
                for (int k2 = 0; k2 < 2; ++k2) {
                    const int kb = c * 2 + k2;
                    f16x8 af = *(const f16x8*)(ar + kb * 64);
                    f16x8 w3 = *(const f16x8*)(wr + kb * 1024);
                    acc0 = MFMA16(af, BC16(g0[kb]), acc0);
                    acc1 = MFMA16(af, BC16(g1[kb]), acc1);
                    if (kb < 15) {
                        acc2 = MFMA16(af, BC16(g2[kb]), acc2);
                    } else {
                        f16x8 w2t = *(const f16x8*)(wr + 16384);
                        acc2 = MFMA16(af, w2t, acc2);
                    }
                    acc3 = MFMA16(af, w3, acc3);
                }
            }
            __builtin_amdgcn_sched_barrier(0);
        }

        // epilogue: tanh, global store (overwrite xp[t] with h[t]), h write
        char* aw = lds + WLDS_B + ((t & 1) * ABUF_SZ);
#pragma unroll
        for (int s = 0; s < 2; ++s) {
            char* aws = aw + (s ? awr1 : awr0);
#pragma unroll
            for (int r = 0; r < 4; ++r) {
                const float aa = (lq < 2)
                    ? (s == 0 ? acc0[r] : acc1[r])
                    : (s == 0 ? acc2[r] : acc3[r]);
                const float v = tanh_fast(aa + xv[s][r]);
                *(float*)(pb + xoff[s][r]) = v;
                *(_Float16*)(aws + r * ABUF_P) = (_Float16)v;
            }
        }
        __syncthreads();
    }
}

// ---------------------------------------------------------------------------
extern "C" void kernel_launch(void* const* d_in, const int* in_sizes, int n_in,
                              void* d_out, int out_size, void* d_ws, size_t ws_size,
                              hipStream_t stream) {
    const float* x   = (const float*)d_in[0];
    const float* wih = (const float*)d_in[1];
    const float* whh = (const float*)d_in[2];
    const float* bih = (const float*)d_in[3];
    const float* bhh = (const float*)d_in[4];
    float* out = (float*)d_out;

    dim3 g1(HH / P1_TN, (BB * SS) / P1_TM);
    xp_gemm<<<g1, 256, 0, stream>>>(x, wih, bih, bhh, out);

    static_assert(LDS_TOT6 <= 163840, "LDS over 160 KiB");
    hipFuncSetAttribute((const void*)rnn_scan6,
                        hipFuncAttributeMaxDynamicSharedMemorySize, LDS_TOT6);
    rnn_scan6<<<dim3(1), dim3(512), LDS_TOT6, stream>>>(whh, out);
}